// Round 1
// 629.371 us; speedup vs baseline: 1.0592x; 1.0592x over previous
//
#include <hip/hip_runtime.h>
#include <math.h>

#define NVIEW 720
#define NDCT  1024
#define NZ    32
#define NX    512
#define NY    512

#define NR 24        // staged detector rows (16-wide x tile: i0 spread <= 23, exact)
#define RSTRIDE 20   // dwords per staged row (16 data + 4 pad; 80 B).
                     // Bank-group of chunk c in row r = (5r + c) mod 8, injective in
                     // r mod 8 -> only dr in {8,16} alias; measured ~0.75 cyc/read (ok).
                     // Do NOT swizzle chunks (R3 regression); aligned-16B mapping cannot
                     // avoid dr=8 aliases (pigeonhole over 8 slots).

typedef unsigned int uint;

#if __has_builtin(__builtin_amdgcn_fdot2)
#define USE_FDOT2 1
typedef _Float16 half2v __attribute__((ext_vector_type(2)));
#else
#define USE_FDOT2 0
#endif

// Round fp32 -> bf16 bits (RNE).
__device__ __forceinline__ uint f2bf_rne(float f) {
    uint u = __float_as_uint(f);
    return (u + 0x7fffu + ((u >> 16) & 1u)) >> 16;
}

// Packed word for (v, i, z):
//  fdot2 path:  lo16 = f16(g0 = p[i]), hi16 = f16(d = p[i+1]-p[i])
//               consumer: acc = v_dot2_f32_f16(word, {1.0, w}, acc)  -- 1 VALU/sample
//  fallback:    hi16 = dithered bf16(g0), lo16 = bf16(d)             -- 3 VALU/sample
__device__ __forceinline__ uint pack_word(float a, float b) {
#if USE_FDOT2
    union { _Float16 h[2]; uint u; } r;
    r.h[0] = (_Float16)a;         // g0 in low half
    r.h[1] = (_Float16)(b - a);   // d  in high half
    return r.u;
#else
    uint lo = f2bf_rne(b - a);
    uint u  = (f2bf_rne(a) << 16) | lo;
    uint up = u + 0x10000u, um = u - 0x10000u;
    float e0 = fabsf(__uint_as_float(u)  - a);
    float e1 = fabsf(__uint_as_float(up) - a);
    float e2 = fabsf(__uint_as_float(um) - a);
    if (e1 < e0) { u = up; e0 = e1; }
    if (e2 < e0) { u = um; }
    return u;
#endif
}

// packed[v][i][z], z contiguous (32 dw per (v,i)).
// Input x: (Z=32, 1, NVIEW, NDCT); proj[v][z][i] = x[z][0][v][i].
// One wave per (v, 64-i block): coalesced reads, LDS stride-33 transpose
// (conflict-free), fully coalesced x4 writes.
__global__ __launch_bounds__(64) void pack_kernel(const float* __restrict__ x,
                                                  uint* __restrict__ packed) {
    __shared__ uint tr[64 * 33];             // [i_local][z], stride 33 -> conflict-free
    const int l  = threadIdx.x;              // 0..63
    const int v  = blockIdx.x;               // 0..719
    const int ib = blockIdx.y * 64;          // i block base
    const bool last = (ib + 64 >= NDCT);
    const float* rowbase = x + (size_t)v * NDCT + ib;

    // Preload the "i = ib+64" boundary value for all 32 z into lanes 0..31.
    float pre = 0.0f;
    if (l < NZ && !last) pre = rowbase[(size_t)l * (NVIEW * NDCT) + 64];

    for (int z = 0; z < NZ; ++z) {
        const float* r = rowbase + (size_t)z * (NVIEW * NDCT);
        float a   = r[l];                    // coalesced 256B
        float a64 = __shfl(pre, z);
        float b   = __shfl(a, l + 1);
        if (l == 63) b = a64;                // neighbor across wave boundary
        tr[l * 33 + z] = pack_word(a, b);
    }
    __syncthreads();

    uint* obase = packed + ((size_t)v * NDCT + ib) * 32;
    #pragma unroll
    for (int it = 0; it < 8; ++it) {
        int c  = it * 64 + l;                // chunk 0..511; dst dword = 4c (coalesced)
        int il = c >> 3;
        int zc = (c & 7) * 4;
        uint4 w4;
        w4.x = tr[il * 33 + zc + 0];
        w4.y = tr[il * 33 + zc + 1];
        w4.z = tr[il * 33 + zc + 2];
        w4.w = tr[il * 33 + zc + 3];
        *(uint4*)(obase + (size_t)c * 4) = w4;
    }
}

#if USE_FDOT2
// 1 VALU op per sample: acc = g0*1 + d*w + acc  (products in f32)
#define SAMP(A, zz, uu, WP, WF) do { \
    union { uint q; half2v h; } _c; _c.q = (uu); \
    A[zz] = __builtin_amdgcn_fdot2(_c.h, (WP), A[zz], false); \
} while (0)
#else
// 3 VALU ops per sample (bf16 fallback).
#define SAMP(A, zz, uu, WP, WF) do { \
    A[zz] += __uint_as_float(uu); \
    A[zz]  = fmaf((WF), __uint_as_float((uu) << 16), A[zz]); \
} while (0)
#endif

#define SAMPLE16(A, WP, WF) do { \
    SAMP(A, 0, q0.x, WP, WF); SAMP(A, 1, q0.y, WP, WF); \
    SAMP(A, 2, q0.z, WP, WF); SAMP(A, 3, q0.w, WP, WF); \
    SAMP(A, 4, q1.x, WP, WF); SAMP(A, 5, q1.y, WP, WF); \
    SAMP(A, 6, q1.z, WP, WF); SAMP(A, 7, q1.w, WP, WF); \
    SAMP(A, 8, q2.x, WP, WF); SAMP(A, 9, q2.y, WP, WF); \
    SAMP(A,10, q2.z, WP, WF); SAMP(A,11, q2.w, WP, WF); \
    SAMP(A,12, q3.x, WP, WF); SAMP(A,13, q3.y, WP, WF); \
    SAMP(A,14, q3.z, WP, WF); SAMP(A,15, q3.w, WP, WF); \
} while (0)

// 16x16 pixel tile, 128 threads (8x16): each thread owns pixels (x0, x0+1)
// at the same y, 16 z. px1's detector position differs from px0 by exactly c,
// so with prob (1-|c|) it reads the SAME staged row -> the second gather is
// issued under the divergent mask (i1 != i0); inactive lanes keep px0's row
// in q (correct for them), active lanes overwrite. Avg ~36% of second-gather
// bank traffic eliminated, zero select/copy ops.
// Per-view uniform state is ONE float4 LDS read: {c, s, 511.5-imin, bits(imin)},
// software-pipelined so the v+1 read also provides the staging base.
__global__ __launch_bounds__(128, 4) void bp_lds(const uint* __restrict__ packed,
                                                 float* __restrict__ out) {
    __shared__ float4 tab[NVIEW];                           // 11520 B
    __shared__ __align__(16) uint stage[2][NR * RSTRIDE];   // 2 x 1920 B

    const int tid = threadIdx.y * 8 + threadIdx.x;          // 0..127
    const int g   = blockIdx.z;                              // z-group (16 z each)
    const float xf0 = (float)(int)(blockIdx.x * 16) - 255.5f;
    const float yf0 = (float)(int)(blockIdx.y * 16) - 255.5f;

    // Per-view cos/sin + block-uniform floor(t_min) folded as bval = 511.5 - imin.
    // Corner eval uses the same fmaf nesting as the per-thread t; folding bval
    // perturbs t by <= 1 ULP(512) ~ 1.2e-4: trunc at 0 and NR slack absorb it
    // (exact spread <= 21.3 + 1 -> rl <= 22 < 24 even with fuzz).
    for (int v = tid; v < NVIEW; v += 128) {
        float th = (float)v * (float)(M_PI / NVIEW);
        float s, c;
        sincosf(th, &s, &c);
        float b0 = fmaf(yf0, s, 511.5f);
        float b1 = fmaf(yf0 + 15.0f, s, 511.5f);
        float t00 = fmaf(xf0, c, b0);
        float t10 = fmaf(xf0 + 15.0f, c, b0);
        float t01 = fmaf(xf0, c, b1);
        float t11 = fmaf(xf0 + 15.0f, c, b1);
        int imin = (int)fminf(fminf(t00, t10), fminf(t01, t11));
        tab[v] = make_float4(c, s, 511.5f - (float)imin, __int_as_float(imin));
    }
    __syncthreads();

    const int x0 = blockIdx.x * 16 + threadIdx.x * 2;       // even
    const int y  = blockIdx.y * 16 + threadIdx.y;
    const float xf = (float)x0 - 255.5f;
    const float yf = (float)y  - 255.5f;

    float acc0[16], acc1[16];
    #pragma unroll
    for (int z = 0; z < 16; ++z) { acc0[z] = 0.0f; acc1[z] = 0.0f; }

    // Staging: NR rows x 16 dw = 96 x4-chunks over 2 waves (48 lanes each).
    const int  wv   = tid >> 6;
    const int  ln   = tid & 63;
    const bool sact = (ln < 48);
    const int  slot = wv * 48 + ln;          // 0..95
    const int  sr   = slot >> 2;             // staged row 0..23
    const int  sch  = slot & 3;              // 16B chunk 0..3
    const size_t sg_off = ((size_t)sr << 5) + (g << 4) + (sch << 2);   // global dw off
    const int  swr  = sr * RSTRIDE + (sch << 2);                        // LDS dw off

    float4 t4 = tab[0];
    uint4 st;
    if (sact) {  // prologue: stage view 0 into buffer 0
        st = *(const uint4*)(packed + ((size_t)__float_as_int(t4.w) << 5) + sg_off);
        *(uint4*)&stage[0][swr] = st;
    }
    __syncthreads();

    #pragma unroll 2
    for (int v = 0; v < NVIEW; ++v) {
        // [A] pipelined uniform read for v+1 (feeds staging now, main path next iter)
        float4 t4n = t4;
        if (v + 1 < NVIEW) t4n = tab[v + 1];
        if (sact && v + 1 < NVIEW) {
            st = *(const uint4*)(packed + ((size_t)(v + 1) << 15)
                                 + ((size_t)__float_as_int(t4n.w) << 5) + sg_off);
        }

        const float c = t4.x;
        float t0 = fmaf(xf, c, fmaf(yf, t4.y, t4.z));   // t - imin, >= -1ulp
        float t1 = t0 + c;
        int   i0 = (int)t0;                              // trunc(-eps) = 0: safe
        int   i1 = (int)t1;
        float w0 = t0 - (float)i0;
        float w1 = t1 - (float)i1;

#if USE_FDOT2
        half2v wp0; wp0[0] = (_Float16)1.0f; wp0[1] = (_Float16)w0;
        half2v wp1; wp1[0] = (_Float16)1.0f; wp1[1] = (_Float16)w1;
#else
        const int wp0 = 0, wp1 = 0;  // unused tokens in fallback
#endif

        // [C] px0 gather: 4x b128 off one base (imm offsets 0/64/128/192 B)
        const uint* sp = stage[v & 1] + i0 * RSTRIDE;
        uint4 q0 = *(const uint4*)(sp);
        uint4 q1 = *(const uint4*)(sp + 4);
        uint4 q2 = *(const uint4*)(sp + 8);
        uint4 q3 = *(const uint4*)(sp + 12);

        SAMPLE16(acc0, wp0, w0);

        // [D] px1 gather only where the row differs (divergent mask; inactive
        // lanes keep px0's row in q, which is exactly px1's row for them)
        if (i1 != i0) {
            const uint* sp1 = stage[v & 1] + i1 * RSTRIDE;
            q0 = *(const uint4*)(sp1);
            q1 = *(const uint4*)(sp1 + 4);
            q2 = *(const uint4*)(sp1 + 8);
            q3 = *(const uint4*)(sp1 + 12);
        }

        SAMPLE16(acc1, wp1, w1);

        // [F] publish view v+1 stage (vmcnt waits only on st, issued at [A])
        if (sact && v + 1 < NVIEW) *(uint4*)&stage[(v + 1) & 1][swr] = st;
        // [G] one barrier per view: orders iter-(v+1) writes of a buffer after
        // all iter-v reads of it -> race-free double buffer
        __syncthreads();
        t4 = t4n;
    }

    const float scale = 0.0043633231299858236f;  // pi / 720
    #pragma unroll
    for (int lz = 0; lz < 16; ++lz) {
        float2 o = make_float2(acc0[lz] * scale, acc1[lz] * scale);
        *(float2*)(out + (((size_t)(g * 16 + lz)) * NY + y) * NX + x0) = o;
    }
}

// Fallback (ws too small for packed array): direct fp32, two loads per sample.
__global__ __launch_bounds__(256) void bp_direct(const float* __restrict__ xin,
                                                 float* __restrict__ out) {
    __shared__ float2 cs[NVIEW];
    int lt = threadIdx.y * 64 + threadIdx.x;
    for (int v = lt; v < NVIEW; v += 256) {
        float th = (float)v * (float)(M_PI / NVIEW);
        float s, c;
        sincosf(th, &s, &c);
        cs[v] = make_float2(c, s);
    }
    __syncthreads();

    int x = blockIdx.x * 64 + threadIdx.x;
    int y = blockIdx.y * 4 + threadIdx.y;
    float xf = (float)x - 255.5f;
    float yf = (float)y - 255.5f;

    float acc[NZ];
    #pragma unroll
    for (int z = 0; z < NZ; ++z) acc[z] = 0.0f;

    for (int v = 0; v < NVIEW; ++v) {
        float2 a = cs[v];
        float t  = fmaf(xf, a.x, fmaf(yf, a.y, 511.5f));
        int   i0 = (int)t;
        float w  = t - (float)i0;
        const float* p = xin + (size_t)v * NDCT + i0;
        #pragma unroll
        for (int z = 0; z < NZ; ++z) {
            float g0 = p[(size_t)z * NVIEW * NDCT];
            float g1 = p[(size_t)z * NVIEW * NDCT + 1];
            acc[z] += fmaf(w, g1 - g0, g0);
        }
    }

    const float scale = 0.0043633231299858236f;
    #pragma unroll
    for (int z = 0; z < NZ; ++z) {
        out[((size_t)z * NY + y) * NX + x] = acc[z] * scale;
    }
}

extern "C" void kernel_launch(void* const* d_in, const int* in_sizes, int n_in,
                              void* d_out, int out_size, void* d_ws, size_t ws_size,
                              hipStream_t stream) {
    const float* x = (const float*)d_in[0];
    float* out = (float*)d_out;

    const size_t packed_bytes = (size_t)NVIEW * NDCT * NZ * sizeof(uint);  // 94.4 MB

    if (ws_size >= packed_bytes) {
        uint* packed = (uint*)d_ws;
        pack_kernel<<<dim3(NVIEW, NDCT / 64), 64, 0, stream>>>(x, packed);
        bp_lds<<<dim3(NX / 16, NY / 16, 2), dim3(8, 16), 0, stream>>>(packed, out);
    } else {
        bp_direct<<<dim3(NX / 64, NY / 4), dim3(64, 4), 0, stream>>>(x, out);
    }
}